// Round 4
// baseline (357.370 us; speedup 1.0000x reference)
//
#include <hip/hip_runtime.h>
#include <math.h>

#define EC_N 64
// exp(-0.5*q) == exp2(q * -0.5*log2(e)); fold the scale into the coefficients
#define NEG_HALF_LOG2E (-0.72134752044448170368f)
#define NEG_LOG2E      (-1.44269504088896340736f)
#define PTS_PER_THREAD 4

typedef float v4f __attribute__((ext_vector_type(4)));

struct __align__(16) NerfParam {
    // q' = c00*x*x + c11*y*y + c22*z*z + c01_2*x*y + c02_2*x*z + c12_2*y*z
    // coefficients pre-scaled by -0.5*log2(e) so rbf = exp2(q') * cc
    float c00, c11, c22, c01_2;
    float c02_2, c12_2, cx, cy;
    float cz, cc, pad0, pad1;
};

__device__ __forceinline__ float fast_exp2(float x) { return __builtin_amdgcn_exp2f(x); }
__device__ __forceinline__ float fast_rcp(float x)  { return __builtin_amdgcn_rcpf(x); }
__device__ __forceinline__ v4f nt_load(const v4f* p) { return __builtin_nontemporal_load(p); }

__global__ void init_penalty_kernel(const float* __restrict__ centers,
                                    float* __restrict__ pen_out) {
    int e = threadIdx.x;
    float p = 0.f;
    if (e < EC_N) {
        const float bmax[3] = {0.6f, 0.6f, 0.6f};
        const float bmin[3] = {-0.6f, -0.6f, -0.35f};
        #pragma unroll
        for (int k = 0; k < 3; ++k) {
            float cv = centers[e * 3 + k];
            p += fmaxf(cv - bmax[k], 0.f) + fmaxf(bmin[k] - cv, 0.f);
        }
    }
    #pragma unroll
    for (int off = 32; off > 0; off >>= 1)
        p += __shfl_down(p, off, 64);
    if (threadIdx.x == 0) *pen_out = p;   // main kernel atomicAdds on top
}

__global__ __launch_bounds__(256, 2) void rbf_main_kernel(
    const float* __restrict__ wsp,        // [N,3]
    const float* __restrict__ act,        // [EC,N,4]
    const float* __restrict__ dists,      // [N,1]
    const float* __restrict__ constants,  // [EC,1]
    const float* __restrict__ centers,    // [EC,3]
    const float* __restrict__ radii,      // [EC,3]
    const float* __restrict__ rotations,  // [EC,3]
    float* __restrict__ out,              // [N,4]
    float* __restrict__ pen,              // scalar (pre-initialized with bbox term)
    int n)
{
    __shared__ NerfParam sp[EC_N];
    __shared__ float s_pen[4];

    const int tid = threadIdx.x;

    // ---- per-block nerflet parameter setup (redundant across blocks, tiny) ----
    if (tid < EC_N) {
        const int e = tid;
        float c = fabsf(constants[e]);
        float r0 = fabsf(radii[e * 3 + 0]) + 0.005f;
        float r1 = fabsf(radii[e * 3 + 1]) + 0.005f;
        float r2 = fabsf(radii[e * 3 + 2]) + 0.005f;
        float d0 = 1.f / (r0 + 1e-8f);
        float d1 = 1.f / (r1 + 1e-8f);
        float d2 = 1.f / (r2 + 1e-8f);
        float ax = rotations[e * 3 + 0];
        float ay = rotations[e * 3 + 1];
        float az = rotations[e * 3 + 2];
        float sx, cx, sy, cy, sz, cz;
        sincosf(ax, &sx, &cx);
        sincosf(ay, &sy, &cy);
        sincosf(az, &sz, &cz);
        float R00 = cz * cy;
        float R01 = cz * sy * sx - sz * cx;
        float R02 = cz * sy * cx + sz * sx;
        float R10 = sz * cy;
        float R11 = sz * sy * sx + cz * cx;
        float R12 = sz * sy * cx - cz * sx;
        float R20 = -sy;
        float R21 = cy * sx;
        float R22 = cy * cx;
        const float k = NEG_HALF_LOG2E;
        float c00 = (R00 * R00 * d0 + R01 * R01 * d1 + R02 * R02 * d2) * k;
        float c11 = (R10 * R10 * d0 + R11 * R11 * d1 + R12 * R12 * d2) * k;
        float c22 = (R20 * R20 * d0 + R21 * R21 * d1 + R22 * R22 * d2) * k;
        float c01 = (R00 * R10 * d0 + R01 * R11 * d1 + R02 * R12 * d2) * k;
        float c02 = (R00 * R20 * d0 + R01 * R21 * d1 + R02 * R22 * d2) * k;
        float c12 = (R10 * R20 * d0 + R11 * R21 * d1 + R12 * R22 * d2) * k;
        NerfParam p;
        p.c00 = c00; p.c11 = c11; p.c22 = c22;
        p.c01_2 = 2.f * c01; p.c02_2 = 2.f * c02; p.c12_2 = 2.f * c12;
        p.cx = centers[e * 3 + 0];
        p.cy = centers[e * 3 + 1];
        p.cz = centers[e * 3 + 2];
        p.cc = c;
        p.pad0 = 0.f; p.pad1 = 0.f;
        sp[e] = p;
    }
    __syncthreads();

    // 4 points per thread, interleaved by 256 so each wave-load stays 1KB-coalesced
    // and the block's 16 loads per e cover one contiguous 16KB window.
    const int base = blockIdx.x * (256 * PTS_PER_THREAD) + tid;
    int   idx[PTS_PER_THREAD];
    bool  okk[PTS_PER_THREAD];
    float px[PTS_PER_THREAD], py[PTS_PER_THREAD], pz[PTS_PER_THREAD], dl[PTS_PER_THREAD];
    #pragma unroll
    for (int k = 0; k < PTS_PER_THREAD; ++k) {
        const int i = base + k * 256;
        okk[k] = i < n;
        idx[k] = okk[k] ? i : 0;
        px[k] = wsp[idx[k] * 3 + 0];
        py[k] = wsp[idx[k] * 3 + 1];
        pz[k] = wsp[idx[k] * 3 + 2];
        dl[k] = dists[idx[k]] * NEG_LOG2E;   // alpha = 1 - exp2(relu(w)*dl)
    }

    const v4f* pact = (const v4f*)act;

    // prefetch buffers: distance 2 along e
    v4f buf0[PTS_PER_THREAD], buf1[PTS_PER_THREAD];
    #pragma unroll
    for (int k = 0; k < PTS_PER_THREAD; ++k)
        buf0[k] = nt_load(pact + (size_t)0 * n + idx[k]);
    #pragma unroll
    for (int k = 0; k < PTS_PER_THREAD; ++k)
        buf1[k] = nt_load(pact + (size_t)1 * n + idx[k]);

    float S[PTS_PER_THREAD], v0[PTS_PER_THREAD], v1[PTS_PER_THREAD],
          v2[PTS_PER_THREAD], v3[PTS_PER_THREAD];
    #pragma unroll
    for (int k = 0; k < PTS_PER_THREAD; ++k) {
        S[k] = 0.f; v0[k] = 0.f; v1[k] = 0.f; v2[k] = 0.f; v3[k] = 0.f;
    }
    float penL = 0.f;

    #pragma unroll 2
    for (int e = 0; e < EC_N; ++e) {
        v4f a[PTS_PER_THREAD];
        const bool even = (e & 1) == 0;      // folds under unroll 2
        #pragma unroll
        for (int k = 0; k < PTS_PER_THREAD; ++k)
            a[k] = even ? buf0[k] : buf1[k];

        if (e < EC_N - 2) {                  // uniform branch: prefetch row e+2
            const v4f* row = pact + (size_t)(e + 2) * n;
            #pragma unroll
            for (int k = 0; k < PTS_PER_THREAD; ++k) {
                const v4f t = nt_load(row + idx[k]);
                if (even) buf0[k] = t; else buf1[k] = t;
            }
        }

        const NerfParam p = sp[e];
        #pragma unroll
        for (int k = 0; k < PTS_PER_THREAD; ++k) {
            const float x = px[k] - p.cx, y = py[k] - p.cy, z = pz[k] - p.cz;
            float q = x * x * p.c00;
            q = fmaf(y * y, p.c11, q);
            q = fmaf(z * z, p.c22, q);
            q = fmaf(x * y, p.c01_2, q);
            q = fmaf(x * z, p.c02_2, q);
            q = fmaf(y * z, p.c12_2, q);
            const float rbf = fast_exp2(q) * p.cc;
            S[k] += rbf;
            penL += okk[k] ? fmaxf(rbf - 0.01f, 0.f) : 0.f;
            const float s0 = fast_rcp(1.f + fast_exp2(a[k].x * NEG_LOG2E));
            const float s1 = fast_rcp(1.f + fast_exp2(a[k].y * NEG_LOG2E));
            const float s2 = fast_rcp(1.f + fast_exp2(a[k].z * NEG_LOG2E));
            const float al = 1.f - fast_exp2(fmaxf(a[k].w, 0.f) * dl[k]);
            v0[k] = fmaf(rbf, s0, v0[k]);
            v1[k] = fmaf(rbf, s1, v1[k]);
            v2[k] = fmaf(rbf, s2, v2[k]);
            v3[k] = fmaf(rbf, al, v3[k]);
        }
    }

    #pragma unroll
    for (int k = 0; k < PTS_PER_THREAD; ++k) {
        if (okk[k]) {
            const float inv = fast_rcp(S[k] + 1e-6f);
            v4f o;
            o.x = v0[k] * inv; o.y = v1[k] * inv; o.z = v2[k] * inv; o.w = v3[k] * inv;
            __builtin_nontemporal_store(o, (v4f*)out + idx[k]);
        }
    }

    // ---- penalty reduction: shuffle within wave, LDS across waves, one atomic/block ----
    float penLocal = penL;
    #pragma unroll
    for (int off = 32; off > 0; off >>= 1)
        penLocal += __shfl_down(penLocal, off, 64);
    const int wave = tid >> 6;
    const int lane = tid & 63;
    if (lane == 0) s_pen[wave] = penLocal;
    __syncthreads();
    if (tid == 0) {
        const float t = s_pen[0] + s_pen[1] + s_pen[2] + s_pen[3];
        atomicAdd(pen, t * (0.001f / (float)n));
    }
}

extern "C" void kernel_launch(void* const* d_in, const int* in_sizes, int n_in,
                              void* d_out, int out_size, void* d_ws, size_t ws_size,
                              hipStream_t stream) {
    const float* wsp       = (const float*)d_in[0];
    const float* act       = (const float*)d_in[1];
    const float* dists     = (const float*)d_in[2];
    const float* constants = (const float*)d_in[3];
    const float* centers   = (const float*)d_in[4];
    const float* radii     = (const float*)d_in[5];
    const float* rotations = (const float*)d_in[6];

    const int n = in_sizes[0] / 3;           // world_space_points is [N,3]
    float* out = (float*)d_out;              // [N,4] flat
    float* pen = out + (size_t)n * 4;        // scalar penalty at the end

    init_penalty_kernel<<<1, 64, 0, stream>>>(centers, pen);

    const int pts_per_block = 256 * PTS_PER_THREAD;
    const int blocks = (n + pts_per_block - 1) / pts_per_block;   // 256 blocks at N=262144
    rbf_main_kernel<<<blocks, 256, 0, stream>>>(
        wsp, act, dists, constants, centers, radii, rotations, out, pen, n);
}